// Round 15
// baseline (355.017 us; speedup 1.0000x reference)
//
#include <hip/hip_runtime.h>

#define NB 8
#define NT 1024
#define NE 128
#define NH 8
#define NS 16

// Workspace layout (floats). Q/Kc/Vc/Y are each B*H*T*S = 1048576 floats (4 MB).
// Kc/Vc hold mask-COMPACTED keys/values (first vcount[b] rows valid per bh).
#define WS_Q 0
#define WS_KC 1048576
#define WS_VC 2097152
#define WS_Y 3145728
#define WS_VCNT 4194304

#define WT_PITCH 132  // multiple of 4 -> every row 16B-aligned for float4 LDS reads

typedef float v2f __attribute__((ext_vector_type(2)));

static __device__ __forceinline__ v2f vlo(const float4 v) { return v2f{v.x, v.y}; }
static __device__ __forceinline__ v2f vhi(const float4 v) { return v2f{v.z, v.w}; }
static __device__ __forceinline__ v2f pfma(v2f a, v2f b, v2f c) {
  return __builtin_elementwise_fma(a, b, c);  // v_pk_fma_f32 on gfx950
}

// fast 2^x: v_exp_f32 directly (avoids glibc __exp2f macro collision)
static __device__ __forceinline__ float fexp2(float x) {
  return __builtin_amdgcn_exp2f(x);
}

// packed fma4: 2 v_pk_fma_f32 instead of 4 v_fma_f32
static __device__ __forceinline__ void fma4(float4& acc, float s, const float4 v) {
  v2f lo = pfma(v2f{s, s}, vlo(v), vlo(acc));
  v2f hi = pfma(v2f{s, s}, vhi(v), vhi(acc));
  acc.x = lo.x; acc.y = lo.y; acc.z = hi.x; acc.w = hi.y;
}

// Packed-FP32 dot of two 16-float vectors.
static __device__ __forceinline__ float dot16p(const float4 q0, const float4 q1,
                                               const float4 q2, const float4 q3,
                                               const float4 k0, const float4 k1,
                                               const float4 k2, const float4 k3) {
  v2f a = vlo(q0) * vlo(k0);
  v2f b = vhi(q0) * vhi(k0);
  a = pfma(vlo(q1), vlo(k1), a);
  b = pfma(vhi(q1), vhi(k1), b);
  a = pfma(vlo(q2), vlo(k2), a);
  b = pfma(vhi(q2), vhi(k2), b);
  a = pfma(vlo(q3), vlo(k3), a);
  b = pfma(vhi(q3), vhi(k3), b);
  v2f c = a + b;
  return c.x + c.y;
}

// ---------------- Kernel A: QKV projection + in-block mask compaction ----
// grid = 1024, 256 thr. block -> (h = blk&7, rowgroup = blk>>3 of 64 rows).
// Block computes the mask prefix for its 64 rows (depends only on `masks`)
// and writes K/V directly COMPACTED into Kc/Vc[bh][pos][16]. Q uncompacted.
// Q scale folds log2(e) so attn can use v_exp_f32 (2^x) directly.
__global__ __launch_bounds__(256) void qkv_kernel(
    const float* __restrict__ x, const int* __restrict__ masks,
    const float* __restrict__ Wq, const float* __restrict__ Wk,
    const float* __restrict__ Wv, float* __restrict__ Q,
    float* __restrict__ Kc, float* __restrict__ Vc, int* __restrict__ vcount) {
  __shared__ __align__(16) float xs[64 * 20];  // 5120 B, pitch 20
  __shared__ int posl[64];
  const int tid = threadIdx.x;
  const int h = blockIdx.x & 7;
  const int rg = blockIdx.x >> 3;  // 0..127
  const int b = rg >> 4;
  const int bt = (rg & 15) << 6;  // batch-local row base
  {
    const int sr = tid >> 2, sq = tid & 3;
    float4 xv =
        *(const float4*)(x + (size_t)(b * NT + bt + sr) * 128 + h * 16 + sq * 4);
    *(float4*)(xs + sr * 20 + sq * 4) = xv;
  }
  if (tid < 64) {
    int cnt = 0;
    for (int c = 0; c < bt; c += 64)
      cnt += __popcll(__ballot(masks[b * NT + c + tid] != 0));
    int v = masks[b * NT + bt + tid] != 0;
    unsigned long long bal = __ballot(v);
    posl[tid] = v ? (cnt + __popcll(bal & ((1ull << tid) - 1ull))) : -1;
    if (bt == NT - 64 && tid == 0) vcount[b] = cnt + __popcll(bal);
  }
  const int d = tid & 15;
  const int r = (tid >> 4) << 2;
  const float4* wq4 = (const float4*)(Wq + d * 16);
  const float4 wq0 = wq4[0], wq1 = wq4[1], wq2 = wq4[2], wq3 = wq4[3];
  const float4* wk4 = (const float4*)(Wk + d * 16);
  const float4 wk0 = wk4[0], wk1 = wk4[1], wk2 = wk4[2], wk3 = wk4[3];
  const float4* wv4 = (const float4*)(Wv + d * 16);
  const float4 wv0 = wv4[0], wv1 = wv4[1], wv2 = wv4[2], wv3 = wv4[3];
  // log2(e) / sqrt(128): attn computes p = exp2(q.k) = exp(q.k/sqrt(E))
  const float invs = 0.12751744448143132f;
  __syncthreads();
#pragma unroll
  for (int i = 0; i < 4; i++) {
    const int row = r + i;
    const float4* xp = (const float4*)(xs + row * 20);
    const float4 x0 = xp[0], x1 = xp[1], x2 = xp[2], x3 = xp[3];
    float aq = dot16p(x0, x1, x2, x3, wq0, wq1, wq2, wq3);
    float ak = dot16p(x0, x1, x2, x3, wk0, wk1, wk2, wk3);
    float av = dot16p(x0, x1, x2, x3, wv0, wv1, wv2, wv3);
    const int t = bt + row;
    Q[((size_t)(b * NH + h) * NT + t) * NS + d] = aq * invs;
    const int pp = posl[row];
    if (pp >= 0) {
      size_t oc = ((size_t)(b * NH + h) * NT + pp) * NS + d;
      Kc[oc] = ak;
      Vc[oc] = av;
    }
  }
}

// ---------------- Kernel B: 16-wave barrier-free split-K attention -------
// Round-14: 44.4us. Budget: VALU ~21us/SIMD + DS ~20us/CU + stage ~4us,
// wall ~= their SUM -> pipes not overlapping at 2 waves/SIMD TLP (unroll-2
// within-wave ILP gained only 1.5us -> exhausted). Round-15: DOUBLE TLP
// with zero added work: 1024-thread blocks (16 key-split waves), same 256
// blocks -> 4 waves/SIMD. Invariants: each K/V row still ds_read exactly
// once per block (DS/CU unchanged); VALU/CU unchanged; per-wave keys halve.
// Scheduler can now overlap one wave's ds_read chain with another's pfmas.
// Epilogue: 16 splits don't fit LDS at once (80KB) -> two 8-split groups
// per phase, partials kept in registers.
// Carried: Kc/Vc pre-compacted; K/V staged once (64KB); barrier-free main
// loop; fixed m=0 softmax (validated r10/r12); exp2 w/ folded log2e;
// fully-unrolled epilogue indices (r12 rule).
__global__ __launch_bounds__(1024, 4) void attn_kernel(
    const float* __restrict__ Q, const float* __restrict__ Kc,
    const float* __restrict__ Vc, const int* __restrict__ masks,
    const int* __restrict__ vcount, float* __restrict__ Y) {
  __shared__ __align__(16) float smem[16384];  // 65536 B
  float* Ks = smem;          // [512][16]
  float* Vs = smem + 8192;   // [512][16]
  const int tid = threadIdx.x;
  const int lane = tid & 63;
  const int s = tid >> 6;  // key-split 0..15 (= wave id)
  const int bh = blockIdx.x & 63;
  const int qg = blockIdx.x >> 6;  // 0..3
  const int b = bh >> 3, h = bh & 7;
  const int tbase = qg << 8;  // 256 queries per block
  const int nv = vcount[b];

  float4 q[4][4];
#pragma unroll
  for (int qq = 0; qq < 4; qq++) {
    const float4* qg4 =
        (const float4*)(Q + ((size_t)bh * NT + tbase + (qq << 6) + lane) * NS);
    q[qq][0] = qg4[0]; q[qq][1] = qg4[1]; q[qq][2] = qg4[2]; q[qq][3] = qg4[3];
  }
  v2f o[4][8];
  float l[4];
#pragma unroll
  for (int qq = 0; qq < 4; qq++) {
    l[qq] = 0.f;
#pragma unroll
    for (int k = 0; k < 8; k++) o[qq][k] = v2f{0.f, 0.f};
  }

  const int quad = tid & 3;
  const int jr = tid >> 2;  // 0..255

#pragma unroll 1
  for (int k0 = 0; k0 < nv; k0 += 512) {
    const int chunk = (nv - k0 < 512) ? (nv - k0) : 512;
    __syncthreads();  // previous chunk's compute done before overwrite
    // 1024 threads stage 512 rows: 2 passes of K, 2 of V
#pragma unroll 1
    for (int p = 0; p < 2; p++) {
      const int row = jr + (p << 8);
      float4 kv = {0, 0, 0, 0};
      if (row < chunk)
        kv = *(const float4*)(Kc + ((size_t)bh * NT + (k0 + row)) * NS +
                              (quad << 2));
      *(float4*)(Ks + row * 16 + (quad << 2)) = kv;
    }
#pragma unroll 1
    for (int p = 0; p < 2; p++) {
      const int row = jr + (p << 8);
      float4 vv = {0, 0, 0, 0};
      if (row < chunk)
        vv = *(const float4*)(Vc + ((size_t)bh * NT + (k0 + row)) * NS +
                              (quad << 2));
      *(float4*)(Vs + row * 16 + (quad << 2)) = vv;
    }
    __syncthreads();
    // barrier-free compute; wave s handles rows s + g*64 + i*16
#pragma unroll 2
    for (int g = 0; g < 8; g++) {
      const int rb = s + (g << 6);
      if (rb >= chunk) break;  // wave-uniform
      float sc[4][4];
#pragma unroll
      for (int i = 0; i < 4; i++) {
        const float4* kr = (const float4*)(Ks + (rb + (i << 4)) * 16);
        const float4 k0v = kr[0], k1v = kr[1], k2v = kr[2], k3v = kr[3];
#pragma unroll
        for (int qq = 0; qq < 4; qq++)
          sc[qq][i] =
              dot16p(q[qq][0], q[qq][1], q[qq][2], q[qq][3], k0v, k1v, k2v, k3v);
      }
#pragma unroll
      for (int i = 0; i < 4; i++)
        if (rb + (i << 4) >= chunk) {
          sc[0][i] = -1e30f; sc[1][i] = -1e30f;
          sc[2][i] = -1e30f; sc[3][i] = -1e30f;
        }
      float p[4][4];
#pragma unroll
      for (int qq = 0; qq < 4; qq++) {
        p[qq][0] = fexp2(sc[qq][0]);
        p[qq][1] = fexp2(sc[qq][1]);
        p[qq][2] = fexp2(sc[qq][2]);
        p[qq][3] = fexp2(sc[qq][3]);
        l[qq] += (p[qq][0] + p[qq][1]) + (p[qq][2] + p[qq][3]);
      }
#pragma unroll
      for (int i = 0; i < 4; i++) {
        const float4* vr = (const float4*)(Vs + (rb + (i << 4)) * 16);
        const float4 v0 = vr[0], v1 = vr[1], v2 = vr[2], v3 = vr[3];
#pragma unroll
        for (int qq = 0; qq < 4; qq++) {
          const v2f pq = {p[qq][i], p[qq][i]};
          o[qq][0] = pfma(pq, vlo(v0), o[qq][0]);
          o[qq][1] = pfma(pq, vhi(v0), o[qq][1]);
          o[qq][2] = pfma(pq, vlo(v1), o[qq][2]);
          o[qq][3] = pfma(pq, vhi(v1), o[qq][3]);
          o[qq][4] = pfma(pq, vlo(v2), o[qq][4]);
          o[qq][5] = pfma(pq, vhi(v2), o[qq][5]);
          o[qq][6] = pfma(pq, vlo(v3), o[qq][6]);
          o[qq][7] = pfma(pq, vhi(v3), o[qq][7]);
        }
      }
    }
  }

  // ---- epilogue: 4 phases x 2 split-groups; plain-sum merge (fixed m) ----
  // om: [8 splits][64 lanes][20] = 40960 B, aliases Ks (reused per group).
  // All indices compile-time (r12 rule); sub-group partials in registers.
  float* om = smem;
  const int q8 = tid >> 3;  // 0..127 (only <64 used)
  const int sub = tid & 7;
#pragma unroll
  for (int ph = 0; ph < 4; ph++) {
    v2f ysum = {0.f, 0.f};
    float Lsum = 0.f;
    // group A: splits 0-7 write, all reduce partial
    __syncthreads();
    if (s < 8) {
      float* pa = om + (s * 64 + lane) * 20;
#pragma unroll
      for (int k = 0; k < 8; k++) *(v2f*)(pa + k * 2) = o[ph][k];
      pa[16] = l[ph];
    }
    __syncthreads();
    if (tid < 512) {
#pragma unroll
      for (int ss = 0; ss < 8; ss++) {
        const float* pp = om + (ss * 64 + q8) * 20;
        Lsum += pp[16];
        ysum += *(const v2f*)(pp + sub * 2);
      }
    }
    // group B: splits 8-15 write, finish
    __syncthreads();
    if (s >= 8) {
      float* pa = om + ((s - 8) * 64 + lane) * 20;
#pragma unroll
      for (int k = 0; k < 8; k++) *(v2f*)(pa + k * 2) = o[ph][k];
      pa[16] = l[ph];
    }
    __syncthreads();
    if (tid < 512) {
#pragma unroll
      for (int ss = 0; ss < 8; ss++) {
        const float* pp = om + (ss * 64 + q8) * 20;
        Lsum += pp[16];
        ysum += *(const v2f*)(pp + sub * 2);
      }
      const int tq = tbase + (ph << 6) + q8;
      const int qm = masks[b * NT + tq];
      const float inv = (qm != 0 && Lsum > 0.f) ? (1.0f / Lsum) : 0.f;
      ysum *= v2f{inv, inv};
      *(v2f*)(Y + ((size_t)b * NT + tq) * NE + h * NS + sub * 2) = ysum;
    }
  }
}

// ---------------- Kernel C: out = Y @ Wu^T + bu --------------------------
// grid = B*T/16 = 512 blocks, 256 threads. 16 rows/block. attn writes ALL
// query rows of Y (masked -> 0 via inv=0), so no mask handling needed here.
__global__ __launch_bounds__(256) void proj_kernel(
    const float* __restrict__ Y, const float* __restrict__ Wu,
    const float* __restrict__ bu, float* __restrict__ out) {
  __shared__ __align__(16) float Wt[64 * WT_PITCH];  // 33792 B
  __shared__ __align__(16) float Yt[16 * 128];       // 8192 B
  const int tid = threadIdx.x;
  const int r0 = blockIdx.x * 16;
  const float4* yg = (const float4*)(Y + (size_t)r0 * 128);
  float4* yt4 = (float4*)Yt;
  yt4[tid] = yg[tid];
  yt4[tid + 256] = yg[tid + 256];
  const int c0 = (tid & 31) << 2;
  const int rg = (tid >> 5) & 3;
  const int eh = tid >> 7;  // 0 or 1
  float4 acc0 = {0, 0, 0, 0}, acc1 = {0, 0, 0, 0}, acc2 = {0, 0, 0, 0},
         acc3 = {0, 0, 0, 0};
  for (int e0 = 0; e0 < 128; e0 += 64) {
    __syncthreads();  // guards Yt staging (iter 0) and Wt reuse (iter 1)
#pragma unroll
    for (int p = 0; p < 8; p++) {
      int idx = tid + p * 256;
      int c = idx >> 4;
      int es = (idx & 15) << 2;
      float4 w = *(const float4*)(Wu + c * 128 + e0 + es);
      Wt[(es + 0) * WT_PITCH + c] = w.x;
      Wt[(es + 1) * WT_PITCH + c] = w.y;
      Wt[(es + 2) * WT_PITCH + c] = w.z;
      Wt[(es + 3) * WT_PITCH + c] = w.w;
    }
    __syncthreads();
    const int eb = eh << 5;  // this thread's e-half within the 64-chunk
    const float* y0 = Yt + (rg * 4 + 0) * 128 + e0 + eb;
    const float* y1 = Yt + (rg * 4 + 1) * 128 + e0 + eb;
    const float* y2 = Yt + (rg * 4 + 2) * 128 + e0 + eb;
    const float* y3 = Yt + (rg * 4 + 3) * 128 + e0 + eb;
#pragma unroll 4
    for (int e = 0; e < 32; e += 4) {
      const float* wb = Wt + (eb + e) * WT_PITCH + c0;
      float4 w0 = *(const float4*)(wb + 0 * WT_PITCH);
      float4 w1 = *(const float4*)(wb + 1 * WT_PITCH);
      float4 w2 = *(const float4*)(wb + 2 * WT_PITCH);
      float4 w3 = *(const float4*)(wb + 3 * WT_PITCH);
      float4 ya = *(const float4*)(y0 + e);
      float4 yb = *(const float4*)(y1 + e);
      float4 yc = *(const float4*)(y2 + e);
      float4 yd = *(const float4*)(y3 + e);
      fma4(acc0, ya.x, w0); fma4(acc0, ya.y, w1); fma4(acc0, ya.z, w2); fma4(acc0, ya.w, w3);
      fma4(acc1, yb.x, w0); fma4(acc1, yb.y, w1); fma4(acc1, yb.z, w2); fma4(acc1, yb.w, w3);
      fma4(acc2, yc.x, w0); fma4(acc2, yc.y, w1); fma4(acc2, yc.z, w2); fma4(acc2, yc.w, w3);
      fma4(acc3, yd.x, w0); fma4(acc3, yd.y, w1); fma4(acc3, yd.z, w2); fma4(acc3, yd.w, w3);
    }
  }
  // combine e-halves through LDS (Wt dead; pitch 20 to spread banks)
  __syncthreads();
  if (eh == 1) {
    float* p = Wt + (tid & 127) * 20;
    *(float4*)(p + 0) = acc0; *(float4*)(p + 4) = acc1;
    *(float4*)(p + 8) = acc2; *(float4*)(p + 12) = acc3;
  }
  __syncthreads();
  if (eh == 0) {
    const float* p = Wt + tid * 20;
    float4 b4 = *(const float4*)(bu + c0);
    float4 q0 = *(const float4*)(p + 0);
    float4 q1 = *(const float4*)(p + 4);
    float4 q2 = *(const float4*)(p + 8);
    float4 q3 = *(const float4*)(p + 12);
    acc0.x += q0.x + b4.x; acc0.y += q0.y + b4.y; acc0.z += q0.z + b4.z; acc0.w += q0.w + b4.w;
    acc1.x += q1.x + b4.x; acc1.y += q1.y + b4.y; acc1.z += q1.z + b4.z; acc1.w += q1.w + b4.w;
    acc2.x += q2.x + b4.x; acc2.y += q2.y + b4.y; acc2.z += q2.z + b4.z; acc2.w += q2.w + b4.w;
    acc3.x += q3.x + b4.x; acc3.y += q3.y + b4.y; acc3.z += q3.z + b4.z; acc3.w += q3.w + b4.w;
    *(float4*)(out + (size_t)(r0 + rg * 4 + 0) * 128 + c0) = acc0;
    *(float4*)(out + (size_t)(r0 + rg * 4 + 1) * 128 + c0) = acc1;
    *(float4*)(out + (size_t)(r0 + rg * 4 + 2) * 128 + c0) = acc2;
    *(float4*)(out + (size_t)(r0 + rg * 4 + 3) * 128 + c0) = acc3;
  }
}

extern "C" void kernel_launch(void* const* d_in, const int* in_sizes, int n_in,
                              void* d_out, int out_size, void* d_ws,
                              size_t ws_size, hipStream_t stream) {
  const float* x = (const float*)d_in[0];
  const int* masks = (const int*)d_in[1];
  const float* Wq = (const float*)d_in[2];
  const float* Wk = (const float*)d_in[3];
  const float* Wv = (const float*)d_in[4];
  const float* Wu = (const float*)d_in[5];
  const float* bu = (const float*)d_in[6];
  float* out = (float*)d_out;

  float* ws = (float*)d_ws;
  float* Q = ws + WS_Q;
  float* Kc = ws + WS_KC;
  float* Vc = ws + WS_VC;
  float* Y = ws + WS_Y;
  int* vcount = (int*)(ws + WS_VCNT);

  qkv_kernel<<<1024, 256, 0, stream>>>(x, masks, Wq, Wk, Wv, Q, Kc, Vc,
                                       vcount);
  // grid = 4 query-groups (256 q) x 64 bh = 256 blocks (1/CU), 1024 thr
  attn_kernel<<<4 * NB * NH, 1024, 0, stream>>>(Q, Kc, Vc, masks, vcount, Y);
  proj_kernel<<<NB * NT / 16, 256, 0, stream>>>(Y, Wu, bu, out);
}

// Round 16
// 354.252 us; speedup vs baseline: 1.0022x; 1.0022x over previous
//
#include <hip/hip_runtime.h>

#define NB 8
#define NT 1024
#define NE 128
#define NH 8
#define NS 16

// Workspace layout (floats). Q/Kc/Vc/Y are each B*H*T*S = 1048576 floats (4 MB).
// Kc/Vc hold mask-COMPACTED keys/values (first vcount[b] rows valid per bh).
#define WS_Q 0
#define WS_KC 1048576
#define WS_VC 2097152
#define WS_Y 3145728
#define WS_VCNT 4194304

#define WT_PITCH 132  // multiple of 4 -> every row 16B-aligned for float4 LDS reads

typedef float v2f __attribute__((ext_vector_type(2)));

static __device__ __forceinline__ v2f vlo(const float4 v) { return v2f{v.x, v.y}; }
static __device__ __forceinline__ v2f vhi(const float4 v) { return v2f{v.z, v.w}; }
static __device__ __forceinline__ v2f pfma(v2f a, v2f b, v2f c) {
  return __builtin_elementwise_fma(a, b, c);  // v_pk_fma_f32 on gfx950
}

// fast 2^x: v_exp_f32 directly (avoids glibc __exp2f macro collision)
static __device__ __forceinline__ float fexp2(float x) {
  return __builtin_amdgcn_exp2f(x);
}

// packed fma4: 2 v_pk_fma_f32 instead of 4 v_fma_f32
static __device__ __forceinline__ void fma4(float4& acc, float s, const float4 v) {
  v2f lo = pfma(v2f{s, s}, vlo(v), vlo(acc));
  v2f hi = pfma(v2f{s, s}, vhi(v), vhi(acc));
  acc.x = lo.x; acc.y = lo.y; acc.z = hi.x; acc.w = hi.y;
}

// Packed-FP32 dot of two 16-float vectors.
static __device__ __forceinline__ float dot16p(const float4 q0, const float4 q1,
                                               const float4 q2, const float4 q3,
                                               const float4 k0, const float4 k1,
                                               const float4 k2, const float4 k3) {
  v2f a = vlo(q0) * vlo(k0);
  v2f b = vhi(q0) * vhi(k0);
  a = pfma(vlo(q1), vlo(k1), a);
  b = pfma(vhi(q1), vhi(k1), b);
  a = pfma(vlo(q2), vlo(k2), a);
  b = pfma(vhi(q2), vhi(k2), b);
  a = pfma(vlo(q3), vlo(k3), a);
  b = pfma(vhi(q3), vhi(k3), b);
  v2f c = a + b;
  return c.x + c.y;
}

// ---------------- Kernel A: QKV projection + in-block mask compaction ----
// grid = 1024, 256 thr. block -> (h = blk&7, rowgroup = blk>>3 of 64 rows).
// Block computes the mask prefix for its 64 rows (depends only on `masks`)
// and writes K/V directly COMPACTED into Kc/Vc[bh][pos][16]. Q uncompacted.
// Q scale folds log2(e) so attn can use v_exp_f32 (2^x) directly.
__global__ __launch_bounds__(256) void qkv_kernel(
    const float* __restrict__ x, const int* __restrict__ masks,
    const float* __restrict__ Wq, const float* __restrict__ Wk,
    const float* __restrict__ Wv, float* __restrict__ Q,
    float* __restrict__ Kc, float* __restrict__ Vc, int* __restrict__ vcount) {
  __shared__ __align__(16) float xs[64 * 20];  // 5120 B, pitch 20
  __shared__ int posl[64];
  const int tid = threadIdx.x;
  const int h = blockIdx.x & 7;
  const int rg = blockIdx.x >> 3;  // 0..127
  const int b = rg >> 4;
  const int bt = (rg & 15) << 6;  // batch-local row base
  {
    const int sr = tid >> 2, sq = tid & 3;
    float4 xv =
        *(const float4*)(x + (size_t)(b * NT + bt + sr) * 128 + h * 16 + sq * 4);
    *(float4*)(xs + sr * 20 + sq * 4) = xv;
  }
  if (tid < 64) {
    int cnt = 0;
    for (int c = 0; c < bt; c += 64)
      cnt += __popcll(__ballot(masks[b * NT + c + tid] != 0));
    int v = masks[b * NT + bt + tid] != 0;
    unsigned long long bal = __ballot(v);
    posl[tid] = v ? (cnt + __popcll(bal & ((1ull << tid) - 1ull))) : -1;
    if (bt == NT - 64 && tid == 0) vcount[b] = cnt + __popcll(bal);
  }
  const int d = tid & 15;
  const int r = (tid >> 4) << 2;
  const float4* wq4 = (const float4*)(Wq + d * 16);
  const float4 wq0 = wq4[0], wq1 = wq4[1], wq2 = wq4[2], wq3 = wq4[3];
  const float4* wk4 = (const float4*)(Wk + d * 16);
  const float4 wk0 = wk4[0], wk1 = wk4[1], wk2 = wk4[2], wk3 = wk4[3];
  const float4* wv4 = (const float4*)(Wv + d * 16);
  const float4 wv0 = wv4[0], wv1 = wv4[1], wv2 = wv4[2], wv3 = wv4[3];
  // log2(e) / sqrt(128): attn computes p = exp2(q.k) = exp(q.k/sqrt(E))
  const float invs = 0.12751744448143132f;
  __syncthreads();
#pragma unroll
  for (int i = 0; i < 4; i++) {
    const int row = r + i;
    const float4* xp = (const float4*)(xs + row * 20);
    const float4 x0 = xp[0], x1 = xp[1], x2 = xp[2], x3 = xp[3];
    float aq = dot16p(x0, x1, x2, x3, wq0, wq1, wq2, wq3);
    float ak = dot16p(x0, x1, x2, x3, wk0, wk1, wk2, wk3);
    float av = dot16p(x0, x1, x2, x3, wv0, wv1, wv2, wv3);
    const int t = bt + row;
    Q[((size_t)(b * NH + h) * NT + t) * NS + d] = aq * invs;
    const int pp = posl[row];
    if (pp >= 0) {
      size_t oc = ((size_t)(b * NH + h) * NT + pp) * NS + d;
      Kc[oc] = ak;
      Vc[oc] = av;
    }
  }
}

// ---------------- Kernel B: 16-wave barrier-free split-K attention -------
// Round-15 post-mortem: __launch_bounds__(1024, 4) -- this ROCm treats the
// 2nd arg as min WORKGROUPS/CU (CUDA semantics): 4 blocks x 16 waves = 64
// waves -> clamped to 32 = 8 waves/SIMD -> 64-VGPR budget -> ~100-VGPR
// state spilled (WRITE 620 MB, 270us). FIX: (1024, 1) = 1 block/CU = 16
// waves = 4 waves/SIMD -> 128-VGPR cap >= ~100 live. Structure unchanged
// from r15 (never actually tested): 16 key-split waves, same 256 blocks,
// DS/CU and VALU/CU invariant vs r14, per-wave keys halved; 4 waves/SIMD
// lets one wave's ds_read chain overlap another's PV pfmas.
// Epilogue: 16 splits in two 8-split LDS groups per phase.
// Carried: Kc/Vc pre-compacted; K/V staged once (64KB); barrier-free main
// loop; fixed m=0 softmax (validated r10/r12); exp2 w/ folded log2e;
// fully-unrolled epilogue indices (r12 rule).
__global__ __launch_bounds__(1024, 1) void attn_kernel(
    const float* __restrict__ Q, const float* __restrict__ Kc,
    const float* __restrict__ Vc, const int* __restrict__ masks,
    const int* __restrict__ vcount, float* __restrict__ Y) {
  __shared__ __align__(16) float smem[16384];  // 65536 B
  float* Ks = smem;          // [512][16]
  float* Vs = smem + 8192;   // [512][16]
  const int tid = threadIdx.x;
  const int lane = tid & 63;
  const int s = tid >> 6;  // key-split 0..15 (= wave id)
  const int bh = blockIdx.x & 63;
  const int qg = blockIdx.x >> 6;  // 0..3
  const int b = bh >> 3, h = bh & 7;
  const int tbase = qg << 8;  // 256 queries per block
  const int nv = vcount[b];

  float4 q[4][4];
#pragma unroll
  for (int qq = 0; qq < 4; qq++) {
    const float4* qg4 =
        (const float4*)(Q + ((size_t)bh * NT + tbase + (qq << 6) + lane) * NS);
    q[qq][0] = qg4[0]; q[qq][1] = qg4[1]; q[qq][2] = qg4[2]; q[qq][3] = qg4[3];
  }
  v2f o[4][8];
  float l[4];
#pragma unroll
  for (int qq = 0; qq < 4; qq++) {
    l[qq] = 0.f;
#pragma unroll
    for (int k = 0; k < 8; k++) o[qq][k] = v2f{0.f, 0.f};
  }

  const int quad = tid & 3;
  const int jr = tid >> 2;  // 0..255

#pragma unroll 1
  for (int k0 = 0; k0 < nv; k0 += 512) {
    const int chunk = (nv - k0 < 512) ? (nv - k0) : 512;
    __syncthreads();  // previous chunk's compute done before overwrite
    // 1024 threads stage 512 rows: 2 passes of K, 2 of V
#pragma unroll 1
    for (int p = 0; p < 2; p++) {
      const int row = jr + (p << 8);
      float4 kv = {0, 0, 0, 0};
      if (row < chunk)
        kv = *(const float4*)(Kc + ((size_t)bh * NT + (k0 + row)) * NS +
                              (quad << 2));
      *(float4*)(Ks + row * 16 + (quad << 2)) = kv;
    }
#pragma unroll 1
    for (int p = 0; p < 2; p++) {
      const int row = jr + (p << 8);
      float4 vv = {0, 0, 0, 0};
      if (row < chunk)
        vv = *(const float4*)(Vc + ((size_t)bh * NT + (k0 + row)) * NS +
                              (quad << 2));
      *(float4*)(Vs + row * 16 + (quad << 2)) = vv;
    }
    __syncthreads();
    // barrier-free compute; wave s handles rows s + g*64 + i*16
#pragma unroll 2
    for (int g = 0; g < 8; g++) {
      const int rb = s + (g << 6);
      if (rb >= chunk) break;  // wave-uniform
      float sc[4][4];
#pragma unroll
      for (int i = 0; i < 4; i++) {
        const float4* kr = (const float4*)(Ks + (rb + (i << 4)) * 16);
        const float4 k0v = kr[0], k1v = kr[1], k2v = kr[2], k3v = kr[3];
#pragma unroll
        for (int qq = 0; qq < 4; qq++)
          sc[qq][i] =
              dot16p(q[qq][0], q[qq][1], q[qq][2], q[qq][3], k0v, k1v, k2v, k3v);
      }
#pragma unroll
      for (int i = 0; i < 4; i++)
        if (rb + (i << 4) >= chunk) {
          sc[0][i] = -1e30f; sc[1][i] = -1e30f;
          sc[2][i] = -1e30f; sc[3][i] = -1e30f;
        }
      float p[4][4];
#pragma unroll
      for (int qq = 0; qq < 4; qq++) {
        p[qq][0] = fexp2(sc[qq][0]);
        p[qq][1] = fexp2(sc[qq][1]);
        p[qq][2] = fexp2(sc[qq][2]);
        p[qq][3] = fexp2(sc[qq][3]);
        l[qq] += (p[qq][0] + p[qq][1]) + (p[qq][2] + p[qq][3]);
      }
#pragma unroll
      for (int i = 0; i < 4; i++) {
        const float4* vr = (const float4*)(Vs + (rb + (i << 4)) * 16);
        const float4 v0 = vr[0], v1 = vr[1], v2 = vr[2], v3 = vr[3];
#pragma unroll
        for (int qq = 0; qq < 4; qq++) {
          const v2f pq = {p[qq][i], p[qq][i]};
          o[qq][0] = pfma(pq, vlo(v0), o[qq][0]);
          o[qq][1] = pfma(pq, vhi(v0), o[qq][1]);
          o[qq][2] = pfma(pq, vlo(v1), o[qq][2]);
          o[qq][3] = pfma(pq, vhi(v1), o[qq][3]);
          o[qq][4] = pfma(pq, vlo(v2), o[qq][4]);
          o[qq][5] = pfma(pq, vhi(v2), o[qq][5]);
          o[qq][6] = pfma(pq, vlo(v3), o[qq][6]);
          o[qq][7] = pfma(pq, vhi(v3), o[qq][7]);
        }
      }
    }
  }

  // ---- epilogue: 4 phases x 2 split-groups; plain-sum merge (fixed m) ----
  // om: [8 splits][64 lanes][20] = 40960 B, aliases Ks (reused per group).
  // All indices compile-time (r12 rule); sub-group partials in registers.
  float* om = smem;
  const int q8 = tid >> 3;  // 0..127 (only <64 used)
  const int sub = tid & 7;
#pragma unroll
  for (int ph = 0; ph < 4; ph++) {
    v2f ysum = {0.f, 0.f};
    float Lsum = 0.f;
    // group A: splits 0-7 write, low half reduces partial
    __syncthreads();
    if (s < 8) {
      float* pa = om + (s * 64 + lane) * 20;
#pragma unroll
      for (int k = 0; k < 8; k++) *(v2f*)(pa + k * 2) = o[ph][k];
      pa[16] = l[ph];
    }
    __syncthreads();
    if (tid < 512) {
#pragma unroll
      for (int ss = 0; ss < 8; ss++) {
        const float* pp = om + (ss * 64 + q8) * 20;
        Lsum += pp[16];
        ysum += *(const v2f*)(pp + sub * 2);
      }
    }
    // group B: splits 8-15 write, finish
    __syncthreads();
    if (s >= 8) {
      float* pa = om + ((s - 8) * 64 + lane) * 20;
#pragma unroll
      for (int k = 0; k < 8; k++) *(v2f*)(pa + k * 2) = o[ph][k];
      pa[16] = l[ph];
    }
    __syncthreads();
    if (tid < 512) {
#pragma unroll
      for (int ss = 0; ss < 8; ss++) {
        const float* pp = om + (ss * 64 + q8) * 20;
        Lsum += pp[16];
        ysum += *(const v2f*)(pp + sub * 2);
      }
      const int tq = tbase + (ph << 6) + q8;
      const int qm = masks[b * NT + tq];
      const float inv = (qm != 0 && Lsum > 0.f) ? (1.0f / Lsum) : 0.f;
      ysum *= v2f{inv, inv};
      *(v2f*)(Y + ((size_t)b * NT + tq) * NE + h * NS + sub * 2) = ysum;
    }
  }
}

// ---------------- Kernel C: out = Y @ Wu^T + bu --------------------------
// grid = B*T/16 = 512 blocks, 256 threads. 16 rows/block. attn writes ALL
// query rows of Y (masked -> 0 via inv=0), so no mask handling needed here.
__global__ __launch_bounds__(256) void proj_kernel(
    const float* __restrict__ Y, const float* __restrict__ Wu,
    const float* __restrict__ bu, float* __restrict__ out) {
  __shared__ __align__(16) float Wt[64 * WT_PITCH];  // 33792 B
  __shared__ __align__(16) float Yt[16 * 128];       // 8192 B
  const int tid = threadIdx.x;
  const int r0 = blockIdx.x * 16;
  const float4* yg = (const float4*)(Y + (size_t)r0 * 128);
  float4* yt4 = (float4*)Yt;
  yt4[tid] = yg[tid];
  yt4[tid + 256] = yg[tid + 256];
  const int c0 = (tid & 31) << 2;
  const int rg = (tid >> 5) & 3;
  const int eh = tid >> 7;  // 0 or 1
  float4 acc0 = {0, 0, 0, 0}, acc1 = {0, 0, 0, 0}, acc2 = {0, 0, 0, 0},
         acc3 = {0, 0, 0, 0};
  for (int e0 = 0; e0 < 128; e0 += 64) {
    __syncthreads();  // guards Yt staging (iter 0) and Wt reuse (iter 1)
#pragma unroll
    for (int p = 0; p < 8; p++) {
      int idx = tid + p * 256;
      int c = idx >> 4;
      int es = (idx & 15) << 2;
      float4 w = *(const float4*)(Wu + c * 128 + e0 + es);
      Wt[(es + 0) * WT_PITCH + c] = w.x;
      Wt[(es + 1) * WT_PITCH + c] = w.y;
      Wt[(es + 2) * WT_PITCH + c] = w.z;
      Wt[(es + 3) * WT_PITCH + c] = w.w;
    }
    __syncthreads();
    const int eb = eh << 5;  // this thread's e-half within the 64-chunk
    const float* y0 = Yt + (rg * 4 + 0) * 128 + e0 + eb;
    const float* y1 = Yt + (rg * 4 + 1) * 128 + e0 + eb;
    const float* y2 = Yt + (rg * 4 + 2) * 128 + e0 + eb;
    const float* y3 = Yt + (rg * 4 + 3) * 128 + e0 + eb;
#pragma unroll 4
    for (int e = 0; e < 32; e += 4) {
      const float* wb = Wt + (eb + e) * WT_PITCH + c0;
      float4 w0 = *(const float4*)(wb + 0 * WT_PITCH);
      float4 w1 = *(const float4*)(wb + 1 * WT_PITCH);
      float4 w2 = *(const float4*)(wb + 2 * WT_PITCH);
      float4 w3 = *(const float4*)(wb + 3 * WT_PITCH);
      float4 ya = *(const float4*)(y0 + e);
      float4 yb = *(const float4*)(y1 + e);
      float4 yc = *(const float4*)(y2 + e);
      float4 yd = *(const float4*)(y3 + e);
      fma4(acc0, ya.x, w0); fma4(acc0, ya.y, w1); fma4(acc0, ya.z, w2); fma4(acc0, ya.w, w3);
      fma4(acc1, yb.x, w0); fma4(acc1, yb.y, w1); fma4(acc1, yb.z, w2); fma4(acc1, yb.w, w3);
      fma4(acc2, yc.x, w0); fma4(acc2, yc.y, w1); fma4(acc2, yc.z, w2); fma4(acc2, yc.w, w3);
      fma4(acc3, yd.x, w0); fma4(acc3, yd.y, w1); fma4(acc3, yd.z, w2); fma4(acc3, yd.w, w3);
    }
  }
  // combine e-halves through LDS (Wt dead; pitch 20 to spread banks)
  __syncthreads();
  if (eh == 1) {
    float* p = Wt + (tid & 127) * 20;
    *(float4*)(p + 0) = acc0; *(float4*)(p + 4) = acc1;
    *(float4*)(p + 8) = acc2; *(float4*)(p + 12) = acc3;
  }
  __syncthreads();
  if (eh == 0) {
    const float* p = Wt + tid * 20;
    float4 b4 = *(const float4*)(bu + c0);
    float4 q0 = *(const float4*)(p + 0);
    float4 q1 = *(const float4*)(p + 4);
    float4 q2 = *(const float4*)(p + 8);
    float4 q3 = *(const float4*)(p + 12);
    acc0.x += q0.x + b4.x; acc0.y += q0.y + b4.y; acc0.z += q0.z + b4.z; acc0.w += q0.w + b4.w;
    acc1.x += q1.x + b4.x; acc1.y += q1.y + b4.y; acc1.z += q1.z + b4.z; acc1.w += q1.w + b4.w;
    acc2.x += q2.x + b4.x; acc2.y += q2.y + b4.y; acc2.z += q2.z + b4.z; acc2.w += q2.w + b4.w;
    acc3.x += q3.x + b4.x; acc3.y += q3.y + b4.y; acc3.z += q3.z + b4.z; acc3.w += q3.w + b4.w;
    *(float4*)(out + (size_t)(r0 + rg * 4 + 0) * 128 + c0) = acc0;
    *(float4*)(out + (size_t)(r0 + rg * 4 + 1) * 128 + c0) = acc1;
    *(float4*)(out + (size_t)(r0 + rg * 4 + 2) * 128 + c0) = acc2;
    *(float4*)(out + (size_t)(r0 + rg * 4 + 3) * 128 + c0) = acc3;
  }
}

extern "C" void kernel_launch(void* const* d_in, const int* in_sizes, int n_in,
                              void* d_out, int out_size, void* d_ws,
                              size_t ws_size, hipStream_t stream) {
  const float* x = (const float*)d_in[0];
  const int* masks = (const int*)d_in[1];
  const float* Wq = (const float*)d_in[2];
  const float* Wk = (const float*)d_in[3];
  const float* Wv = (const float*)d_in[4];
  const float* Wu = (const float*)d_in[5];
  const float* bu = (const float*)d_in[6];
  float* out = (float*)d_out;

  float* ws = (float*)d_ws;
  float* Q = ws + WS_Q;
  float* Kc = ws + WS_KC;
  float* Vc = ws + WS_VC;
  float* Y = ws + WS_Y;
  int* vcount = (int*)(ws + WS_VCNT);

  qkv_kernel<<<1024, 256, 0, stream>>>(x, masks, Wq, Wk, Wv, Q, Kc, Vc,
                                       vcount);
  // grid = 4 query-groups (256 q) x 64 bh = 256 blocks (1/CU), 1024 thr
  attn_kernel<<<4 * NB * NH, 1024, 0, stream>>>(Q, Kc, Vc, masks, vcount, Y);
  proj_kernel<<<NB * NT / 16, 256, 0, stream>>>(Y, Wu, bu, out);
}

// Round 17
// 136.749 us; speedup vs baseline: 2.5961x; 2.5905x over previous
//
#include <hip/hip_runtime.h>

#define NB 8
#define NT 1024
#define NE 128
#define NH 8
#define NS 16

// Workspace (floats): Q/Kc/Vc/Y are each 1048576 (4 MB); L is 64*1024; then vcount.
// Kc/Vc hold mask-COMPACTED keys/values (first vcount[b] rows valid per bh).
// Y and L are ZEROED by qkv each launch and accumulated by attn via atomicAdd
// (fixed-m softmax -> cross-block merge is a plain sum); proj normalizes.
#define WS_Q 0
#define WS_KC 1048576
#define WS_VC 2097152
#define WS_Y 3145728
#define WS_L 4194304
#define WS_VCNT (4194304 + 65536)

#define WT_PITCH 132  // multiple of 4 -> every row 16B-aligned for float4 LDS reads

typedef float v2f __attribute__((ext_vector_type(2)));

static __device__ __forceinline__ v2f vlo(const float4 v) { return v2f{v.x, v.y}; }
static __device__ __forceinline__ v2f vhi(const float4 v) { return v2f{v.z, v.w}; }
static __device__ __forceinline__ v2f pfma(v2f a, v2f b, v2f c) {
  return __builtin_elementwise_fma(a, b, c);  // v_pk_fma_f32 on gfx950
}

// fast 2^x: v_exp_f32 directly (avoids glibc __exp2f macro collision)
static __device__ __forceinline__ float fexp2(float x) {
  return __builtin_amdgcn_exp2f(x);
}

// packed fma4: 2 v_pk_fma_f32 instead of 4 v_fma_f32
static __device__ __forceinline__ void fma4(float4& acc, float s, const float4 v) {
  v2f lo = pfma(v2f{s, s}, vlo(v), vlo(acc));
  v2f hi = pfma(v2f{s, s}, vhi(v), vhi(acc));
  acc.x = lo.x; acc.y = lo.y; acc.z = hi.x; acc.w = hi.y;
}

// Packed-FP32 dot of two 16-float vectors.
static __device__ __forceinline__ float dot16p(const float4 q0, const float4 q1,
                                               const float4 q2, const float4 q3,
                                               const float4 k0, const float4 k1,
                                               const float4 k2, const float4 k3) {
  v2f a = vlo(q0) * vlo(k0);
  v2f b = vhi(q0) * vhi(k0);
  a = pfma(vlo(q1), vlo(k1), a);
  b = pfma(vhi(q1), vhi(k1), b);
  a = pfma(vlo(q2), vlo(k2), a);
  b = pfma(vhi(q2), vhi(k2), b);
  a = pfma(vlo(q3), vlo(k3), a);
  b = pfma(vhi(q3), vhi(k3), b);
  v2f c = a + b;
  return c.x + c.y;
}

// ---------------- Kernel A: QKV projection + compaction + Y/L zeroing ----
// grid = 1024, 256 thr. block -> (h = blk&7, rowgroup = blk>>3 of 64 rows).
// Writes K/V COMPACTED into Kc/Vc[bh][pos][16] (mask prefix computed
// in-block); Q uncompacted, scale folds log2(e). Also zeroes this block's
// Y slice (64 rows x head-16) and L slice (64 entries) so attn can
// accumulate partials with atomicAdd.
__global__ __launch_bounds__(256) void qkv_kernel(
    const float* __restrict__ x, const int* __restrict__ masks,
    const float* __restrict__ Wq, const float* __restrict__ Wk,
    const float* __restrict__ Wv, float* __restrict__ Q,
    float* __restrict__ Kc, float* __restrict__ Vc, float* __restrict__ Y,
    float* __restrict__ L, int* __restrict__ vcount) {
  __shared__ __align__(16) float xs[64 * 20];  // 5120 B, pitch 20
  __shared__ int posl[64];
  const int tid = threadIdx.x;
  const int h = blockIdx.x & 7;
  const int rg = blockIdx.x >> 3;  // 0..127
  const int b = rg >> 4;
  const int bt = (rg & 15) << 6;  // batch-local row base
  {
    const int sr = tid >> 2, sq = tid & 3;
    float4 xv =
        *(const float4*)(x + (size_t)(b * NT + bt + sr) * 128 + h * 16 + sq * 4);
    *(float4*)(xs + sr * 20 + sq * 4) = xv;
    // zero this block's Y region: 64 rows x 16 floats = 256 float4
    *(float4*)(Y + (size_t)(b * NT + bt + sr) * NE + h * NS + sq * 4) =
        float4{0, 0, 0, 0};
  }
  if (tid < 64) {
    L[(size_t)(b * NH + h) * NT + bt + tid] = 0.f;
    int cnt = 0;
    for (int c = 0; c < bt; c += 64)
      cnt += __popcll(__ballot(masks[b * NT + c + tid] != 0));
    int v = masks[b * NT + bt + tid] != 0;
    unsigned long long bal = __ballot(v);
    posl[tid] = v ? (cnt + __popcll(bal & ((1ull << tid) - 1ull))) : -1;
    if (bt == NT - 64 && tid == 0) vcount[b] = cnt + __popcll(bal);
  }
  const int d = tid & 15;
  const int r = (tid >> 4) << 2;
  const float4* wq4 = (const float4*)(Wq + d * 16);
  const float4 wq0 = wq4[0], wq1 = wq4[1], wq2 = wq4[2], wq3 = wq4[3];
  const float4* wk4 = (const float4*)(Wk + d * 16);
  const float4 wk0 = wk4[0], wk1 = wk4[1], wk2 = wk4[2], wk3 = wk4[3];
  const float4* wv4 = (const float4*)(Wv + d * 16);
  const float4 wv0 = wv4[0], wv1 = wv4[1], wv2 = wv4[2], wv3 = wv4[3];
  // log2(e) / sqrt(128): attn computes p = exp2(q.k) = exp(q.k/sqrt(E))
  const float invs = 0.12751744448143132f;
  __syncthreads();
#pragma unroll
  for (int i = 0; i < 4; i++) {
    const int row = r + i;
    const float4* xp = (const float4*)(xs + row * 20);
    const float4 x0 = xp[0], x1 = xp[1], x2 = xp[2], x3 = xp[3];
    float aq = dot16p(x0, x1, x2, x3, wq0, wq1, wq2, wq3);
    float ak = dot16p(x0, x1, x2, x3, wk0, wk1, wk2, wk3);
    float av = dot16p(x0, x1, x2, x3, wv0, wv1, wv2, wv3);
    const int t = bt + row;
    Q[((size_t)(b * NH + h) * NT + t) * NS + d] = aq * invs;
    const int pp = posl[row];
    if (pp >= 0) {
      size_t oc = ((size_t)(b * NH + h) * NT + pp) * NS + d;
      Kc[oc] = ak;
      Vc[oc] = av;
    }
  }
}

// ---------------- Kernel B: key-halved split-K attention, 2 blocks/CU ----
// Round-16 post-mortem: 1024-thread blocks are allocator-poisoned (64 VGPR
// regardless of bounds -> spill). TLP route instead: 2 INDEPENDENT 512-thr
// blocks per CU, each handling HALF the key range -> DS/CU and VALU/CU
// unchanged vs r14 (4096 ds_read, same fma count), but 4 waves/SIMD with NO
// shared barriers between the co-resident blocks: one block's stage phase
// overlaps the other's compute. Fixed-m softmax (r10/r12-validated) makes
// the cross-block merge a plain sum: block reduces its 8 splits in LDS,
// then atomicAdd's one partial per output float into Y/L (pre-zeroed by
// qkv); proj normalizes by L and applies the query mask.
// grid = 2 key-halves x 4 qgroups x 64 bh = 512 blocks, 512 thr,
// 8 key-split waves, 4 queries/thread; LDS 32 KB (256-row K/V chunks).
__global__ __launch_bounds__(512, 2) void attn_kernel(
    const float* __restrict__ Q, const float* __restrict__ Kc,
    const float* __restrict__ Vc, const int* __restrict__ vcount,
    float* __restrict__ Y, float* __restrict__ L) {
  __shared__ __align__(16) float smem[8192];  // 32768 B
  float* Ks = smem;          // [256][16]
  float* Vs = smem + 4096;   // [256][16]
  const int tid = threadIdx.x;
  const int lane = tid & 63;
  const int s = tid >> 6;  // key-split 0..7 (= wave id)
  const int kh = blockIdx.x >> 8;        // key half 0/1
  const int rest = blockIdx.x & 255;
  const int bh = rest & 63;
  const int qg = rest >> 6;  // 0..3
  const int b = bh >> 3, h = bh & 7;
  const int tbase = qg << 8;  // 256 queries per block
  const int nv = vcount[b];
  const int h0 = nv >> 1;
  const int kstart = kh ? h0 : 0;
  const int kend = kh ? nv : h0;

  float4 q[4][4];
#pragma unroll
  for (int qq = 0; qq < 4; qq++) {
    const float4* qg4 =
        (const float4*)(Q + ((size_t)bh * NT + tbase + (qq << 6) + lane) * NS);
    q[qq][0] = qg4[0]; q[qq][1] = qg4[1]; q[qq][2] = qg4[2]; q[qq][3] = qg4[3];
  }
  v2f o[4][8];
  float l[4];
#pragma unroll
  for (int qq = 0; qq < 4; qq++) {
    l[qq] = 0.f;
#pragma unroll
    for (int k = 0; k < 8; k++) o[qq][k] = v2f{0.f, 0.f};
  }

  const int quad = tid & 3;
  const int jr = tid >> 2;  // 0..127

#pragma unroll 1
  for (int k0 = kstart; k0 < kend; k0 += 256) {
    const int chunk = (kend - k0 < 256) ? (kend - k0) : 256;
    __syncthreads();  // previous chunk's compute done before overwrite
#pragma unroll
    for (int p = 0; p < 2; p++) {
      const int row = jr + (p << 7);
      float4 kv = {0, 0, 0, 0};
      if (row < chunk)
        kv = *(const float4*)(Kc + ((size_t)bh * NT + (k0 + row)) * NS +
                              (quad << 2));
      *(float4*)(Ks + row * 16 + (quad << 2)) = kv;
    }
#pragma unroll
    for (int p = 0; p < 2; p++) {
      const int row = jr + (p << 7);
      float4 vv = {0, 0, 0, 0};
      if (row < chunk)
        vv = *(const float4*)(Vc + ((size_t)bh * NT + (k0 + row)) * NS +
                              (quad << 2));
      *(float4*)(Vs + row * 16 + (quad << 2)) = vv;
    }
    __syncthreads();
    // barrier-free compute; wave s handles rows s + g*32 + i*8
#pragma unroll 2
    for (int g = 0; g < 8; g++) {
      const int rb = s + (g << 5);
      if (rb >= chunk) break;  // wave-uniform
      float sc[4][4];
#pragma unroll
      for (int i = 0; i < 4; i++) {
        const float4* kr = (const float4*)(Ks + (rb + (i << 3)) * 16);
        const float4 k0v = kr[0], k1v = kr[1], k2v = kr[2], k3v = kr[3];
#pragma unroll
        for (int qq = 0; qq < 4; qq++)
          sc[qq][i] =
              dot16p(q[qq][0], q[qq][1], q[qq][2], q[qq][3], k0v, k1v, k2v, k3v);
      }
#pragma unroll
      for (int i = 0; i < 4; i++)
        if (rb + (i << 3) >= chunk) {
          sc[0][i] = -1e30f; sc[1][i] = -1e30f;
          sc[2][i] = -1e30f; sc[3][i] = -1e30f;
        }
      float p[4][4];
#pragma unroll
      for (int qq = 0; qq < 4; qq++) {
        p[qq][0] = fexp2(sc[qq][0]);
        p[qq][1] = fexp2(sc[qq][1]);
        p[qq][2] = fexp2(sc[qq][2]);
        p[qq][3] = fexp2(sc[qq][3]);
        l[qq] += (p[qq][0] + p[qq][1]) + (p[qq][2] + p[qq][3]);
      }
#pragma unroll
      for (int i = 0; i < 4; i++) {
        const float4* vr = (const float4*)(Vs + (rb + (i << 3)) * 16);
        const float4 v0 = vr[0], v1 = vr[1], v2 = vr[2], v3 = vr[3];
#pragma unroll
        for (int qq = 0; qq < 4; qq++) {
          const v2f pq = {p[qq][i], p[qq][i]};
          o[qq][0] = pfma(pq, vlo(v0), o[qq][0]);
          o[qq][1] = pfma(pq, vhi(v0), o[qq][1]);
          o[qq][2] = pfma(pq, vlo(v1), o[qq][2]);
          o[qq][3] = pfma(pq, vhi(v1), o[qq][3]);
          o[qq][4] = pfma(pq, vlo(v2), o[qq][4]);
          o[qq][5] = pfma(pq, vhi(v2), o[qq][5]);
          o[qq][6] = pfma(pq, vlo(v3), o[qq][6]);
          o[qq][7] = pfma(pq, vhi(v3), o[qq][7]);
        }
      }
    }
  }

  // ---- epilogue: 4 phases x 2 groups of 4 splits; block partial then
  // one atomicAdd per output float (fixed-m plain-sum merge). All indices
  // compile-time (r12 rule). om [4][64][20] = 20480 B aliases Ks.
  float* om = smem;
  const int q8 = tid >> 3;  // 0..63
  const int sub = tid & 7;  // 0..7
#pragma unroll
  for (int ph = 0; ph < 4; ph++) {
    v2f ysum = {0.f, 0.f};
    float Lsum = 0.f;
    __syncthreads();  // main-loop / previous-phase reads done
    if (s < 4) {
      float* pa = om + (s * 64 + lane) * 20;
#pragma unroll
      for (int k = 0; k < 8; k++) *(v2f*)(pa + k * 2) = o[ph][k];
      pa[16] = l[ph];
    }
    __syncthreads();
#pragma unroll
    for (int ss = 0; ss < 4; ss++) {
      const float* pp = om + (ss * 64 + q8) * 20;
      Lsum += pp[16];
      ysum += *(const v2f*)(pp + sub * 2);
    }
    __syncthreads();
    if (s >= 4) {
      float* pa = om + ((s - 4) * 64 + lane) * 20;
#pragma unroll
      for (int k = 0; k < 8; k++) *(v2f*)(pa + k * 2) = o[ph][k];
      pa[16] = l[ph];
    }
    __syncthreads();
#pragma unroll
    for (int ss = 0; ss < 4; ss++) {
      const float* pp = om + (ss * 64 + q8) * 20;
      Lsum += pp[16];
      ysum += *(const v2f*)(pp + sub * 2);
    }
    const int tq = tbase + (ph << 6) + q8;
    float* yp = Y + ((size_t)b * NT + tq) * NE + h * NS + sub * 2;
    atomicAdd(yp + 0, ysum.x);
    atomicAdd(yp + 1, ysum.y);
    if (sub == 0) atomicAdd(L + (size_t)bh * NT + tq, Lsum);
  }
}

// ---------------- Kernel C: out = (Y/L masked) @ Wu^T + bu ---------------
// grid = B*T/16 = 512 blocks, 256 threads. 16 rows/block. Y holds raw
// partial sums; normalize by L and apply query mask at Yt staging.
__global__ __launch_bounds__(256) void proj_kernel(
    const float* __restrict__ Y, const float* __restrict__ L,
    const int* __restrict__ masks, const float* __restrict__ Wu,
    const float* __restrict__ bu, float* __restrict__ out) {
  __shared__ __align__(16) float Wt[64 * WT_PITCH];  // 33792 B
  __shared__ __align__(16) float Yt[16 * 128];       // 8192 B
  const int tid = threadIdx.x;
  const int r0 = blockIdx.x * 16;
  const int bb = r0 >> 10;  // batch (16-row blocks never straddle batches)
  const float4* yg = (const float4*)(Y + (size_t)r0 * 128);
  float4* yt4 = (float4*)Yt;
  {
#pragma unroll
    for (int p = 0; p < 2; p++) {
      const int idx = tid + p * 256;
      const int row = idx >> 5;        // 0..15
      const int head = (idx & 31) >> 2;  // 0..7
      const int t = (r0 + row) & 1023;
      const float Lv = L[(size_t)(bb * NH + head) * NT + t];
      const int qm = masks[r0 + row];
      const float inv = (qm != 0 && Lv > 0.f) ? (1.0f / Lv) : 0.f;
      float4 v = yg[idx];
      v.x *= inv; v.y *= inv; v.z *= inv; v.w *= inv;
      yt4[idx] = v;
    }
  }
  const int c0 = (tid & 31) << 2;
  const int rg = (tid >> 5) & 3;
  const int eh = tid >> 7;  // 0 or 1
  float4 acc0 = {0, 0, 0, 0}, acc1 = {0, 0, 0, 0}, acc2 = {0, 0, 0, 0},
         acc3 = {0, 0, 0, 0};
  for (int e0 = 0; e0 < 128; e0 += 64) {
    __syncthreads();  // guards Yt staging (iter 0) and Wt reuse (iter 1)
#pragma unroll
    for (int p = 0; p < 8; p++) {
      int idx = tid + p * 256;
      int c = idx >> 4;
      int es = (idx & 15) << 2;
      float4 w = *(const float4*)(Wu + c * 128 + e0 + es);
      Wt[(es + 0) * WT_PITCH + c] = w.x;
      Wt[(es + 1) * WT_PITCH + c] = w.y;
      Wt[(es + 2) * WT_PITCH + c] = w.z;
      Wt[(es + 3) * WT_PITCH + c] = w.w;
    }
    __syncthreads();
    const int eb = eh << 5;  // this thread's e-half within the 64-chunk
    const float* y0 = Yt + (rg * 4 + 0) * 128 + e0 + eb;
    const float* y1 = Yt + (rg * 4 + 1) * 128 + e0 + eb;
    const float* y2 = Yt + (rg * 4 + 2) * 128 + e0 + eb;
    const float* y3 = Yt + (rg * 4 + 3) * 128 + e0 + eb;
#pragma unroll 4
    for (int e = 0; e < 32; e += 4) {
      const float* wb = Wt + (eb + e) * WT_PITCH + c0;
      float4 w0 = *(const float4*)(wb + 0 * WT_PITCH);
      float4 w1 = *(const float4*)(wb + 1 * WT_PITCH);
      float4 w2 = *(const float4*)(wb + 2 * WT_PITCH);
      float4 w3 = *(const float4*)(wb + 3 * WT_PITCH);
      float4 ya = *(const float4*)(y0 + e);
      float4 yb = *(const float4*)(y1 + e);
      float4 yc = *(const float4*)(y2 + e);
      float4 yd = *(const float4*)(y3 + e);
      fma4(acc0, ya.x, w0); fma4(acc0, ya.y, w1); fma4(acc0, ya.z, w2); fma4(acc0, ya.w, w3);
      fma4(acc1, yb.x, w0); fma4(acc1, yb.y, w1); fma4(acc1, yb.z, w2); fma4(acc1, yb.w, w3);
      fma4(acc2, yc.x, w0); fma4(acc2, yc.y, w1); fma4(acc2, yc.z, w2); fma4(acc2, yc.w, w3);
      fma4(acc3, yd.x, w0); fma4(acc3, yd.y, w1); fma4(acc3, yd.z, w2); fma4(acc3, yd.w, w3);
    }
  }
  // combine e-halves through LDS (Wt dead; pitch 20 to spread banks)
  __syncthreads();
  if (eh == 1) {
    float* p = Wt + (tid & 127) * 20;
    *(float4*)(p + 0) = acc0; *(float4*)(p + 4) = acc1;
    *(float4*)(p + 8) = acc2; *(float4*)(p + 12) = acc3;
  }
  __syncthreads();
  if (eh == 0) {
    const float* p = Wt + tid * 20;
    float4 b4 = *(const float4*)(bu + c0);
    float4 q0 = *(const float4*)(p + 0);
    float4 q1 = *(const float4*)(p + 4);
    float4 q2 = *(const float4*)(p + 8);
    float4 q3 = *(const float4*)(p + 12);
    acc0.x += q0.x + b4.x; acc0.y += q0.y + b4.y; acc0.z += q0.z + b4.z; acc0.w += q0.w + b4.w;
    acc1.x += q1.x + b4.x; acc1.y += q1.y + b4.y; acc1.z += q1.z + b4.z; acc1.w += q1.w + b4.w;
    acc2.x += q2.x + b4.x; acc2.y += q2.y + b4.y; acc2.z += q2.z + b4.z; acc2.w += q2.w + b4.w;
    acc3.x += q3.x + b4.x; acc3.y += q3.y + b4.y; acc3.z += q3.z + b4.z; acc3.w += q3.w + b4.w;
    *(float4*)(out + (size_t)(r0 + rg * 4 + 0) * 128 + c0) = acc0;
    *(float4*)(out + (size_t)(r0 + rg * 4 + 1) * 128 + c0) = acc1;
    *(float4*)(out + (size_t)(r0 + rg * 4 + 2) * 128 + c0) = acc2;
    *(float4*)(out + (size_t)(r0 + rg * 4 + 3) * 128 + c0) = acc3;
  }
}

extern "C" void kernel_launch(void* const* d_in, const int* in_sizes, int n_in,
                              void* d_out, int out_size, void* d_ws,
                              size_t ws_size, hipStream_t stream) {
  const float* x = (const float*)d_in[0];
  const int* masks = (const int*)d_in[1];
  const float* Wq = (const float*)d_in[2];
  const float* Wk = (const float*)d_in[3];
  const float* Wv = (const float*)d_in[4];
  const float* Wu = (const float*)d_in[5];
  const float* bu = (const float*)d_in[6];
  float* out = (float*)d_out;

  float* ws = (float*)d_ws;
  float* Q = ws + WS_Q;
  float* Kc = ws + WS_KC;
  float* Vc = ws + WS_VC;
  float* Y = ws + WS_Y;
  float* L = ws + WS_L;
  int* vcount = (int*)(ws + WS_VCNT);

  qkv_kernel<<<1024, 256, 0, stream>>>(x, masks, Wq, Wk, Wv, Q, Kc, Vc, Y, L,
                                       vcount);
  // grid = 2 key-halves x 4 qgroups x 64 bh = 512 blocks (2/CU), 512 thr
  attn_kernel<<<2 * 4 * NB * NH, 512, 0, stream>>>(Q, Kc, Vc, vcount, Y, L);
  proj_kernel<<<NB * NT / 16, 256, 0, stream>>>(Y, L, masks, Wu, bu, out);
}

// Round 18
// 133.588 us; speedup vs baseline: 2.6575x; 1.0237x over previous
//
#include <hip/hip_runtime.h>

#define NB 8
#define NT 1024
#define NE 128
#define NH 8
#define NS 16

// Workspace (floats). Q/Kc/Vc 4 MB each; Y0/Y1 4 MB each (per-key-half raw
// partial outputs); L0/L1 256 KB each (per-key-half softmax denominators);
// vcount. Fixed-m softmax -> cross-half merge is a plain sum, done in proj.
#define WS_Q 0
#define WS_KC 1048576
#define WS_VC 2097152
#define WS_Y0 3145728
#define WS_Y1 4194304
#define WS_L0 5242880
#define WS_L1 (5242880 + 65536)
#define WS_VCNT (5242880 + 131072)

#define WT_PITCH 132  // multiple of 4 -> every row 16B-aligned for float4 LDS reads

typedef float v2f __attribute__((ext_vector_type(2)));

static __device__ __forceinline__ v2f vlo(const float4 v) { return v2f{v.x, v.y}; }
static __device__ __forceinline__ v2f vhi(const float4 v) { return v2f{v.z, v.w}; }
static __device__ __forceinline__ v2f pfma(v2f a, v2f b, v2f c) {
  return __builtin_elementwise_fma(a, b, c);  // v_pk_fma_f32 on gfx950
}

// fast 2^x: v_exp_f32 directly (avoids glibc __exp2f macro collision)
static __device__ __forceinline__ float fexp2(float x) {
  return __builtin_amdgcn_exp2f(x);
}

// packed fma4: 2 v_pk_fma_f32 instead of 4 v_fma_f32
static __device__ __forceinline__ void fma4(float4& acc, float s, const float4 v) {
  v2f lo = pfma(v2f{s, s}, vlo(v), vlo(acc));
  v2f hi = pfma(v2f{s, s}, vhi(v), vhi(acc));
  acc.x = lo.x; acc.y = lo.y; acc.z = hi.x; acc.w = hi.y;
}

// Packed-FP32 dot of two 16-float vectors.
static __device__ __forceinline__ float dot16p(const float4 q0, const float4 q1,
                                               const float4 q2, const float4 q3,
                                               const float4 k0, const float4 k1,
                                               const float4 k2, const float4 k3) {
  v2f a = vlo(q0) * vlo(k0);
  v2f b = vhi(q0) * vhi(k0);
  a = pfma(vlo(q1), vlo(k1), a);
  b = pfma(vhi(q1), vhi(k1), b);
  a = pfma(vlo(q2), vlo(k2), a);
  b = pfma(vhi(q2), vhi(k2), b);
  a = pfma(vlo(q3), vlo(k3), a);
  b = pfma(vhi(q3), vhi(k3), b);
  v2f c = a + b;
  return c.x + c.y;
}

// ---------------- Kernel A: QKV projection + in-block mask compaction ----
// grid = 1024, 256 thr (r14 version -- no Y/L zeroing; every Y0/Y1/L0/L1
// element is written unconditionally by attn). Q scale folds log2(e).
__global__ __launch_bounds__(256) void qkv_kernel(
    const float* __restrict__ x, const int* __restrict__ masks,
    const float* __restrict__ Wq, const float* __restrict__ Wk,
    const float* __restrict__ Wv, float* __restrict__ Q,
    float* __restrict__ Kc, float* __restrict__ Vc, int* __restrict__ vcount) {
  __shared__ __align__(16) float xs[64 * 20];  // 5120 B, pitch 20
  __shared__ int posl[64];
  const int tid = threadIdx.x;
  const int h = blockIdx.x & 7;
  const int rg = blockIdx.x >> 3;  // 0..127
  const int b = rg >> 4;
  const int bt = (rg & 15) << 6;  // batch-local row base
  {
    const int sr = tid >> 2, sq = tid & 3;
    float4 xv =
        *(const float4*)(x + (size_t)(b * NT + bt + sr) * 128 + h * 16 + sq * 4);
    *(float4*)(xs + sr * 20 + sq * 4) = xv;
  }
  if (tid < 64) {
    int cnt = 0;
    for (int c = 0; c < bt; c += 64)
      cnt += __popcll(__ballot(masks[b * NT + c + tid] != 0));
    int v = masks[b * NT + bt + tid] != 0;
    unsigned long long bal = __ballot(v);
    posl[tid] = v ? (cnt + __popcll(bal & ((1ull << tid) - 1ull))) : -1;
    if (bt == NT - 64 && tid == 0) vcount[b] = cnt + __popcll(bal);
  }
  const int d = tid & 15;
  const int r = (tid >> 4) << 2;
  const float4* wq4 = (const float4*)(Wq + d * 16);
  const float4 wq0 = wq4[0], wq1 = wq4[1], wq2 = wq4[2], wq3 = wq4[3];
  const float4* wk4 = (const float4*)(Wk + d * 16);
  const float4 wk0 = wk4[0], wk1 = wk4[1], wk2 = wk4[2], wk3 = wk4[3];
  const float4* wv4 = (const float4*)(Wv + d * 16);
  const float4 wv0 = wv4[0], wv1 = wv4[1], wv2 = wv4[2], wv3 = wv4[3];
  // log2(e) / sqrt(128): attn computes p = exp2(q.k) = exp(q.k/sqrt(E))
  const float invs = 0.12751744448143132f;
  __syncthreads();
#pragma unroll
  for (int i = 0; i < 4; i++) {
    const int row = r + i;
    const float4* xp = (const float4*)(xs + row * 20);
    const float4 x0 = xp[0], x1 = xp[1], x2 = xp[2], x3 = xp[3];
    float aq = dot16p(x0, x1, x2, x3, wq0, wq1, wq2, wq3);
    float ak = dot16p(x0, x1, x2, x3, wk0, wk1, wk2, wk3);
    float av = dot16p(x0, x1, x2, x3, wv0, wv1, wv2, wv3);
    const int t = bt + row;
    Q[((size_t)(b * NH + h) * NT + t) * NS + d] = aq * invs;
    const int pp = posl[row];
    if (pp >= 0) {
      size_t oc = ((size_t)(b * NH + h) * NT + pp) * NS + d;
      Kc[oc] = ak;
      Vc[oc] = av;
    }
  }
}

// ---------------- Kernel B: key-halved attention, 2 blocks/CU, no atomics
// Round-17 post-mortem: 2-blocks/CU structure ran clean (no spill) but the
// merge machinery regressed it: 2.1M global atomicAdds + 16 epilogue
// barriers/block + qkv Y/L-zeroing. Round-18 strips that overhead:
//  - dual output buffers Y0/Y1 + L0/L1: each (kh,qg,bh) block owns its
//    region exclusively -> plain stores, no atomics, no pre-zeroing
//    (epilogue always runs; empty key-range writes 0).
//  - LDS 40960 B (2 blocks x 40960 = 80KB/CU fits) -> epilogue is r14's
//    single-group 8-barrier form (om [8][64][20] aliases Ks+Vs).
// proj merges: Yt = (Y0+Y1) * inv(L0+L1, mask).
// grid = 2 key-halves x 4 qgroups x 64 bh = 512 blocks (2/CU), 512 thr,
// 8 key-split waves, 4 queries/thread, 256-row K/V chunks.
__global__ __launch_bounds__(512, 2) void attn_kernel(
    const float* __restrict__ Q, const float* __restrict__ Kc,
    const float* __restrict__ Vc, const int* __restrict__ vcount,
    float* __restrict__ Y0, float* __restrict__ Y1, float* __restrict__ L0,
    float* __restrict__ L1) {
  __shared__ __align__(16) float smem[10240];  // 40960 B
  float* Ks = smem;          // [256][16]
  float* Vs = smem + 4096;   // [256][16]
  const int tid = threadIdx.x;
  const int lane = tid & 63;
  const int s = tid >> 6;  // key-split 0..7 (= wave id)
  const int kh = blockIdx.x >> 8;  // key half 0/1
  const int rest = blockIdx.x & 255;
  const int bh = rest & 63;
  const int qg = rest >> 6;  // 0..3
  const int b = bh >> 3, h = bh & 7;
  const int tbase = qg << 8;  // 256 queries per block
  const int nv = vcount[b];
  const int h0 = nv >> 1;
  const int kstart = kh ? h0 : 0;
  const int kend = kh ? nv : h0;
  float* Yh = kh ? Y1 : Y0;
  float* Lh = kh ? L1 : L0;

  float4 q[4][4];
#pragma unroll
  for (int qq = 0; qq < 4; qq++) {
    const float4* qg4 =
        (const float4*)(Q + ((size_t)bh * NT + tbase + (qq << 6) + lane) * NS);
    q[qq][0] = qg4[0]; q[qq][1] = qg4[1]; q[qq][2] = qg4[2]; q[qq][3] = qg4[3];
  }
  v2f o[4][8];
  float l[4];
#pragma unroll
  for (int qq = 0; qq < 4; qq++) {
    l[qq] = 0.f;
#pragma unroll
    for (int k = 0; k < 8; k++) o[qq][k] = v2f{0.f, 0.f};
  }

  const int quad = tid & 3;
  const int jr = tid >> 2;  // 0..127

#pragma unroll 1
  for (int k0 = kstart; k0 < kend; k0 += 256) {
    const int chunk = (kend - k0 < 256) ? (kend - k0) : 256;
    __syncthreads();  // previous chunk's compute done before overwrite
#pragma unroll
    for (int p = 0; p < 2; p++) {
      const int row = jr + (p << 7);
      float4 kv = {0, 0, 0, 0};
      if (row < chunk)
        kv = *(const float4*)(Kc + ((size_t)bh * NT + (k0 + row)) * NS +
                              (quad << 2));
      *(float4*)(Ks + row * 16 + (quad << 2)) = kv;
    }
#pragma unroll
    for (int p = 0; p < 2; p++) {
      const int row = jr + (p << 7);
      float4 vv = {0, 0, 0, 0};
      if (row < chunk)
        vv = *(const float4*)(Vc + ((size_t)bh * NT + (k0 + row)) * NS +
                              (quad << 2));
      *(float4*)(Vs + row * 16 + (quad << 2)) = vv;
    }
    __syncthreads();
    // barrier-free compute; wave s handles rows s + g*32 + i*8
#pragma unroll 2
    for (int g = 0; g < 8; g++) {
      const int rb = s + (g << 5);
      if (rb >= chunk) break;  // wave-uniform
      float sc[4][4];
#pragma unroll
      for (int i = 0; i < 4; i++) {
        const float4* kr = (const float4*)(Ks + (rb + (i << 3)) * 16);
        const float4 k0v = kr[0], k1v = kr[1], k2v = kr[2], k3v = kr[3];
#pragma unroll
        for (int qq = 0; qq < 4; qq++)
          sc[qq][i] =
              dot16p(q[qq][0], q[qq][1], q[qq][2], q[qq][3], k0v, k1v, k2v, k3v);
      }
#pragma unroll
      for (int i = 0; i < 4; i++)
        if (rb + (i << 3) >= chunk) {
          sc[0][i] = -1e30f; sc[1][i] = -1e30f;
          sc[2][i] = -1e30f; sc[3][i] = -1e30f;
        }
      float p[4][4];
#pragma unroll
      for (int qq = 0; qq < 4; qq++) {
        p[qq][0] = fexp2(sc[qq][0]);
        p[qq][1] = fexp2(sc[qq][1]);
        p[qq][2] = fexp2(sc[qq][2]);
        p[qq][3] = fexp2(sc[qq][3]);
        l[qq] += (p[qq][0] + p[qq][1]) + (p[qq][2] + p[qq][3]);
      }
#pragma unroll
      for (int i = 0; i < 4; i++) {
        const float4* vr = (const float4*)(Vs + (rb + (i << 3)) * 16);
        const float4 v0 = vr[0], v1 = vr[1], v2 = vr[2], v3 = vr[3];
#pragma unroll
        for (int qq = 0; qq < 4; qq++) {
          const v2f pq = {p[qq][i], p[qq][i]};
          o[qq][0] = pfma(pq, vlo(v0), o[qq][0]);
          o[qq][1] = pfma(pq, vhi(v0), o[qq][1]);
          o[qq][2] = pfma(pq, vlo(v1), o[qq][2]);
          o[qq][3] = pfma(pq, vhi(v1), o[qq][3]);
          o[qq][4] = pfma(pq, vlo(v2), o[qq][4]);
          o[qq][5] = pfma(pq, vhi(v2), o[qq][5]);
          o[qq][6] = pfma(pq, vlo(v3), o[qq][6]);
          o[qq][7] = pfma(pq, vhi(v3), o[qq][7]);
        }
      }
    }
  }

  // ---- epilogue: r14's 8-barrier form; raw partial + L stored (plain) ----
  // om [8][64][20] = 40960 B aliases Ks+Vs. All indices compile-time.
  float* om = smem;
  const int q8 = tid >> 3;  // 0..63
  const int sub = tid & 7;  // 0..7
#pragma unroll
  for (int ph = 0; ph < 4; ph++) {
    __syncthreads();  // main-loop / previous-phase reads done
    {
      float* pa = om + (s * 64 + lane) * 20;
#pragma unroll
      for (int k = 0; k < 8; k++) *(v2f*)(pa + k * 2) = o[ph][k];
      pa[16] = l[ph];
    }
    __syncthreads();
    {
      float Lsum = 0.f;
      v2f ysum = {0.f, 0.f};
#pragma unroll
      for (int ss = 0; ss < 8; ss++) {
        const float* pp = om + (ss * 64 + q8) * 20;
        Lsum += pp[16];
        ysum += *(const v2f*)(pp + sub * 2);
      }
      const int tq = tbase + (ph << 6) + q8;
      *(v2f*)(Yh + ((size_t)b * NT + tq) * NE + h * NS + sub * 2) = ysum;
      if (sub == 0) Lh[(size_t)bh * NT + tq] = Lsum;
    }
  }
}

// ---------------- Kernel C: out = ((Y0+Y1)/(L0+L1) masked) @ Wu^T + bu ---
// grid = B*T/16 = 512 blocks, 256 threads. 16 rows/block. Merge of the two
// key-halves (plain sum, fixed-m softmax) + normalization + query mask
// happen at Yt staging.
__global__ __launch_bounds__(256) void proj_kernel(
    const float* __restrict__ Y0, const float* __restrict__ Y1,
    const float* __restrict__ L0, const float* __restrict__ L1,
    const int* __restrict__ masks, const float* __restrict__ Wu,
    const float* __restrict__ bu, float* __restrict__ out) {
  __shared__ __align__(16) float Wt[64 * WT_PITCH];  // 33792 B
  __shared__ __align__(16) float Yt[16 * 128];       // 8192 B
  const int tid = threadIdx.x;
  const int r0 = blockIdx.x * 16;
  const int bb = r0 >> 10;  // batch (16-row blocks never straddle batches)
  const float4* yg0 = (const float4*)(Y0 + (size_t)r0 * 128);
  const float4* yg1 = (const float4*)(Y1 + (size_t)r0 * 128);
  float4* yt4 = (float4*)Yt;
  {
#pragma unroll
    for (int p = 0; p < 2; p++) {
      const int idx = tid + p * 256;
      const int row = idx >> 5;          // 0..15
      const int head = (idx & 31) >> 2;  // 0..7
      const int t = (r0 + row) & 1023;
      const size_t li = (size_t)(bb * NH + head) * NT + t;
      const float Lv = L0[li] + L1[li];
      const int qm = masks[r0 + row];
      const float inv = (qm != 0 && Lv > 0.f) ? (1.0f / Lv) : 0.f;
      float4 a = yg0[idx];
      float4 c = yg1[idx];
      a.x = (a.x + c.x) * inv; a.y = (a.y + c.y) * inv;
      a.z = (a.z + c.z) * inv; a.w = (a.w + c.w) * inv;
      yt4[idx] = a;
    }
  }
  const int c0 = (tid & 31) << 2;
  const int rg = (tid >> 5) & 3;
  const int eh = tid >> 7;  // 0 or 1
  float4 acc0 = {0, 0, 0, 0}, acc1 = {0, 0, 0, 0}, acc2 = {0, 0, 0, 0},
         acc3 = {0, 0, 0, 0};
  for (int e0 = 0; e0 < 128; e0 += 64) {
    __syncthreads();  // guards Yt staging (iter 0) and Wt reuse (iter 1)
#pragma unroll
    for (int p = 0; p < 8; p++) {
      int idx = tid + p * 256;
      int c = idx >> 4;
      int es = (idx & 15) << 2;
      float4 w = *(const float4*)(Wu + c * 128 + e0 + es);
      Wt[(es + 0) * WT_PITCH + c] = w.x;
      Wt[(es + 1) * WT_PITCH + c] = w.y;
      Wt[(es + 2) * WT_PITCH + c] = w.z;
      Wt[(es + 3) * WT_PITCH + c] = w.w;
    }
    __syncthreads();
    const int eb = eh << 5;  // this thread's e-half within the 64-chunk
    const float* y0 = Yt + (rg * 4 + 0) * 128 + e0 + eb;
    const float* y1 = Yt + (rg * 4 + 1) * 128 + e0 + eb;
    const float* y2 = Yt + (rg * 4 + 2) * 128 + e0 + eb;
    const float* y3 = Yt + (rg * 4 + 3) * 128 + e0 + eb;
#pragma unroll 4
    for (int e = 0; e < 32; e += 4) {
      const float* wb = Wt + (eb + e) * WT_PITCH + c0;
      float4 w0 = *(const float4*)(wb + 0 * WT_PITCH);
      float4 w1 = *(const float4*)(wb + 1 * WT_PITCH);
      float4 w2 = *(const float4*)(wb + 2 * WT_PITCH);
      float4 w3 = *(const float4*)(wb + 3 * WT_PITCH);
      float4 ya = *(const float4*)(y0 + e);
      float4 yb = *(const float4*)(y1 + e);
      float4 yc = *(const float4*)(y2 + e);
      float4 yd = *(const float4*)(y3 + e);
      fma4(acc0, ya.x, w0); fma4(acc0, ya.y, w1); fma4(acc0, ya.z, w2); fma4(acc0, ya.w, w3);
      fma4(acc1, yb.x, w0); fma4(acc1, yb.y, w1); fma4(acc1, yb.z, w2); fma4(acc1, yb.w, w3);
      fma4(acc2, yc.x, w0); fma4(acc2, yc.y, w1); fma4(acc2, yc.z, w2); fma4(acc2, yc.w, w3);
      fma4(acc3, yd.x, w0); fma4(acc3, yd.y, w1); fma4(acc3, yd.z, w2); fma4(acc3, yd.w, w3);
    }
  }
  // combine e-halves through LDS (Wt dead; pitch 20 to spread banks)
  __syncthreads();
  if (eh == 1) {
    float* p = Wt + (tid & 127) * 20;
    *(float4*)(p + 0) = acc0; *(float4*)(p + 4) = acc1;
    *(float4*)(p + 8) = acc2; *(float4*)(p + 12) = acc3;
  }
  __syncthreads();
  if (eh == 0) {
    const float* p = Wt + tid * 20;
    float4 b4 = *(const float4*)(bu + c0);
    float4 q0 = *(const float4*)(p + 0);
    float4 q1 = *(const float4*)(p + 4);
    float4 q2 = *(const float4*)(p + 8);
    float4 q3 = *(const float4*)(p + 12);
    acc0.x += q0.x + b4.x; acc0.y += q0.y + b4.y; acc0.z += q0.z + b4.z; acc0.w += q0.w + b4.w;
    acc1.x += q1.x + b4.x; acc1.y += q1.y + b4.y; acc1.z += q1.z + b4.z; acc1.w += q1.w + b4.w;
    acc2.x += q2.x + b4.x; acc2.y += q2.y + b4.y; acc2.z += q2.z + b4.z; acc2.w += q2.w + b4.w;
    acc3.x += q3.x + b4.x; acc3.y += q3.y + b4.y; acc3.z += q3.z + b4.z; acc3.w += q3.w + b4.w;
    *(float4*)(out + (size_t)(r0 + rg * 4 + 0) * 128 + c0) = acc0;
    *(float4*)(out + (size_t)(r0 + rg * 4 + 1) * 128 + c0) = acc1;
    *(float4*)(out + (size_t)(r0 + rg * 4 + 2) * 128 + c0) = acc2;
    *(float4*)(out + (size_t)(r0 + rg * 4 + 3) * 128 + c0) = acc3;
  }
}

extern "C" void kernel_launch(void* const* d_in, const int* in_sizes, int n_in,
                              void* d_out, int out_size, void* d_ws,
                              size_t ws_size, hipStream_t stream) {
  const float* x = (const float*)d_in[0];
  const int* masks = (const int*)d_in[1];
  const float* Wq = (const float*)d_in[2];
  const float* Wk = (const float*)d_in[3];
  const float* Wv = (const float*)d_in[4];
  const float* Wu = (const float*)d_in[5];
  const float* bu = (const float*)d_in[6];
  float* out = (float*)d_out;

  float* ws = (float*)d_ws;
  float* Q = ws + WS_Q;
  float* Kc = ws + WS_KC;
  float* Vc = ws + WS_VC;
  float* Y0 = ws + WS_Y0;
  float* Y1 = ws + WS_Y1;
  float* L0 = ws + WS_L0;
  float* L1 = ws + WS_L1;
  int* vcount = (int*)(ws + WS_VCNT);

  qkv_kernel<<<1024, 256, 0, stream>>>(x, masks, Wq, Wk, Wv, Q, Kc, Vc,
                                       vcount);
  // grid = 2 key-halves x 4 qgroups x 64 bh = 512 blocks (2/CU), 512 thr
  attn_kernel<<<2 * 4 * NB * NH, 512, 0, stream>>>(Q, Kc, Vc, vcount, Y0, Y1,
                                                   L0, L1);
  proj_kernel<<<NB * NT / 16, 256, 0, stream>>>(Y0, Y1, L0, L1, masks, Wu, bu,
                                                out);
}